// Round 3
// baseline (154.549 us; speedup 1.0000x reference)
//
#include <hip/hip_runtime.h>
#include <math.h>

#define BB 4
#define SS 8192
#define HH 2048
#define EE 16
#define BRD_ 256
#define BSZ 1024   /* block size from _adjust(8192) */
#define NN 8       /* SS/BSZ */
#define NB 32      /* BB*NN */
#define MAXTOK 1720 /* int(8192*0.21000000000000002) */
#define KBUD 1
#define HHALF 1024
#define KQ 16      /* K-split for GEMM1 */

// ---------------- K1: block mean partial sums (memory-bound floor) ----------------
__global__ __launch_bounds__(256) void k_bmean(const float* __restrict__ x,
                                               double* __restrict__ part, int TC, int rows) {
  int wg = blockIdx.x;
  int bn = wg / TC, tc = wg - bn * TC;
  int b = bn >> 3, n = bn & 7;
  int tid = threadIdx.x;
  const float* base = x + ((size_t)(b * SS + n * BSZ + tc * rows) * HH);
  double a0=0,a1=0,a2=0,a3=0,a4=0,a5=0,a6=0,a7=0;
  for (int t = 0; t < rows; ++t) {
    const float4* r = (const float4*)(base + (size_t)t * HH);
    float4 u = r[tid];        // h = tid*4 .. +3
    float4 v = r[tid + 256];  // h = 1024 + tid*4 .. +3
    a0 += u.x; a1 += u.y; a2 += u.z; a3 += u.w;
    a4 += v.x; a5 += v.y; a6 += v.z; a7 += v.w;
  }
  double* p = part + ((size_t)bn * TC + tc) * HH;
  int hA = tid * 4, hB = 1024 + tid * 4;
  p[hA] = a0; p[hA+1] = a1; p[hA+2] = a2; p[hA+3] = a3;
  p[hB] = a4; p[hB+1] = a5; p[hB+2] = a6; p[hB+3] = a7;
}

// ---------------- K2: reduce partials -> block mean (fp64) ----------------
__global__ __launch_bounds__(256) void k_brred(const double* __restrict__ part, int TC,
                                               double* __restrict__ br) {
  int bn = blockIdx.x, tid = threadIdx.x;
  for (int kb = 0; kb < 8; ++kb) {
    int h = tid + kb * 256;
    double s = 0;
    for (int tc = 0; tc < TC; ++tc) s += part[((size_t)bn * TC + tc) * HH + h];
    br[(size_t)bn * HH + h] = s * (1.0 / BSZ);
  }
}

// ---------------- K3: GEMM1 [32,2048]x[2048,256], K-split x J-split, 64 wgs ----------------
__global__ __launch_bounds__(256) void k_g1(const double* __restrict__ br,
    const float* __restrict__ bw1, double* __restrict__ g1part) {
  __shared__ double brs[NB][128];  // 32 KB
  int bid = blockIdx.x;            // 64 wgs: jt = bid>>4 (0..3), kq = bid&15
  int jt = bid >> 4, kq = bid & 15;
  int tid = threadIdx.x;
  int k0 = kq * 128;
  for (int i = 0; i < 16; ++i) {
    int idx = i * 256 + tid; int bn = idx >> 7, kk = idx & 127;
    brs[bn][kk] = br[(size_t)bn * HH + k0 + kk];
  }
  __syncthreads();
  int j = (tid & 63) + jt * 64;    // column 0..255
  int bnq = tid >> 6;              // wave id: 8 bn rows per wave
  double acc[8] = {0,0,0,0,0,0,0,0};
  const float* wp = bw1 + (size_t)k0 * BRD_ + j;
  for (int k = 0; k < 128; ++k) {
    double wv = (double)wp[(size_t)k * BRD_];
    #pragma unroll
    for (int r = 0; r < 8; ++r) acc[r] += brs[bnq * 8 + r][k] * wv;
  }
  #pragma unroll
  for (int r = 0; r < 8; ++r)
    g1part[((size_t)kq * NB + bnq * 8 + r) * BRD_ + j] = acc[r];
}

// ---------------- K4: per-block LN -> GELU -> GEMM2 -> softmax/entropy/argmax ----------------
__global__ __launch_bounds__(256) void k_router2(const double* __restrict__ g1part,
    const float* __restrict__ bb1, const float* __restrict__ lng, const float* __restrict__ lnb,
    const float* __restrict__ bw2, const float* __restrict__ bb2,
    double* __restrict__ ent, float* __restrict__ bwv, int* __restrict__ bwi) {
  __shared__ double tg[BRD_];
  __shared__ double p3[16][EE];
  __shared__ double red[4];
  __shared__ double l2[EE];
  __shared__ double bcast;
  int bn = blockIdx.x, tid = threadIdx.x;

  double a = (double)bb1[tid];
  for (int kq = 0; kq < KQ; ++kq) a += g1part[((size_t)kq * NB + bn) * BRD_ + tid];

  // LayerNorm over 256 outputs (eps=1e-5, population var)
  double v = a;
  for (int o = 32; o; o >>= 1) v += __shfl_down(v, o);
  if ((tid & 63) == 0) red[tid >> 6] = v;
  __syncthreads();
  if (tid == 0) bcast = (red[0] + red[1] + red[2] + red[3]) * (1.0 / BRD_);
  __syncthreads();
  double m = bcast;
  double d = a - m;
  v = d * d;
  for (int o = 32; o; o >>= 1) v += __shfl_down(v, o);
  if ((tid & 63) == 0) red[tid >> 6] = v;
  __syncthreads();
  if (tid == 0) bcast = (red[0] + red[1] + red[2] + red[3]) * (1.0 / BRD_);
  __syncthreads();
  double var = bcast;
  double xn = d / sqrt(var + 1e-5) * (double)lng[tid] + (double)lnb[tid];
  tg[tid] = 0.5 * xn * (1.0 + erf(xn * 0.7071067811865476));  // exact GELU
  __syncthreads();

  // GEMM2 [1,256]x[256,16], thread = (j-chunk, expert)
  {
    int e = tid & 15, jc = tid >> 4;
    double s = 0;
    const float* w2 = bw2 + (size_t)(jc * 16) * EE + e;
    for (int jj = 0; jj < 16; ++jj) s += tg[jc * 16 + jj] * (double)w2[jj * EE];
    p3[jc][e] = s;
  }
  __syncthreads();
  if (tid < EE) {
    double acc = (double)bb2[tid];
    for (int jc = 0; jc < 16; ++jc) acc += p3[jc][tid];
    l2[tid] = acc;
  }
  __syncthreads();

  if (tid == 0) {
    double mx = l2[0];
    for (int e = 1; e < EE; ++e) mx = fmax(mx, l2[e]);
    double se = 0, p[EE];
    for (int e = 0; e < EE; ++e) { p[e] = exp(l2[e] - mx); se += p[e]; }
    double inv = 1.0 / se, entv = 0, mp = -1; int ai = 0;
    for (int e = 0; e < EE; ++e) {
      double pr = p[e] * inv;
      if (pr > mp) { mp = pr; ai = e; }   // first-max, matches argmax
      double q = pr + 1e-10;
      entv -= q * log(q);
    }
    entv /= log(16.0);
    ent[bn] = entv; bwv[bn] = (float)mp; bwi[bn] = ai;
  }
}

// ---------------- K5: mask logic, wave-parallel (KBUD==1 -> kth = max of selected) --------
__global__ void k_flags(const double* __restrict__ ent, int* __restrict__ flags) {
  int l = threadIdx.x;  // 64 lanes, one wave
  const double THR = 0.6 * 1.1;  // 0.66000000000000003
  double e = (l < NB) ? ent[l] : -INFINITY;
  bool m1 = (l < NB) && (e > THR);
  unsigned long long m1mask = __ballot(m1);
  int th = __popcll(m1mask);
  // kth largest (KBUD=1) among mask1-selected = max of selected (-inf if none)
  double sel = m1 ? e : -INFINITY;
  for (int o = 32; o; o >>= 1) sel = fmax(sel, __shfl_xor(sel, o));
  double kth = sel;
  // cond = (th*1024 > 1720) && (th>0) && (1 < th)  <=>  th >= 2
  bool cond = (th >= 2);
  bool m2 = cond ? ((l < NB) && (e > kth)) : m1;
  unsigned long long m2mask = __ballot(m2);
  int cum = __popcll(m2mask & ((2ULL << l) - 1ULL)) * BSZ;  // inclusive prefix
  bool tf = m2 && (cum <= MAXTOK);
  bool bf = (l < NB) && ((!m1) || (m2 && !tf));
  if (l < NB) flags[l] = tf ? 1 : (bf ? 2 : 0);
  unsigned long long tfmask = __ballot(tf);
  if (l == 0) flags[NB] = tfmask ? (__ffsll((unsigned long long)tfmask) - 1) : -1;
}

// ---------------- K6: fill routing for block-routed / zero blocks ----------------
__global__ __launch_bounds__(256) void k_fill(const int* __restrict__ flags,
    const float* __restrict__ bwv, const int* __restrict__ bwi, float* __restrict__ routing) {
  int wg = blockIdx.x;
  int bn = wg >> 3, seg = wg & 7;
  int fl = flags[bn];
  if (fl == 1) return;  // token GEMM path writes these
  int b = bn >> 3, n = bn & 7;
  float4 z = make_float4(0.f, 0.f, 0.f, 0.f);
  float4 val = z;
  int c_hit = -1;
  if (fl == 2) {
    int ai = bwi[bn];
    c_hit = ai >> 2;
    ((float*)&val)[ai & 3] = bwv[bn];
  }
  float4* out = (float4*)(routing + ((size_t)(b * SS + n * BSZ + seg * 128) * EE));
  int tid = threadIdx.x;
  for (int l = 0; l < 2; ++l) {
    int idx = l * 256 + tid;  // 512 float4 = 128 rows x 4
    int c = idx & 3;
    out[idx] = (c == c_hit) ? val : z;
  }
}

// ---------------- K7: token GEMM (only the flagged block; others exit) ----------------
__global__ __launch_bounds__(256) void k_tokgemm(const float* __restrict__ x,
    const float* __restrict__ tw1, const float* __restrict__ tb1, const float* __restrict__ tw2,
    const int* __restrict__ flags, float* __restrict__ lpart) {
  int fb = flags[NB];
  if (fb < 0) return;
  int b = fb >> 3, n = fb & 7;
  int tg = blockIdx.x >> 4, nc = blockIdx.x & 15;
  int t0 = tg * 64, j0 = nc * 64;
  const float* xb = x + ((size_t)(b * SS + n * BSZ + t0) * HH);
  __shared__ float xs[64][33];
  __shared__ float wsm[32][65];
  __shared__ float ths[64][65];
  int tid = threadIdx.x;
  int tr = tid >> 4, tc = tid & 15;
  float acc[4][4];
  for (int i = 0; i < 4; ++i)
    for (int j = 0; j < 4; ++j) acc[i][j] = tb1[j0 + tc + j * 16];
  for (int k0 = 0; k0 < HH; k0 += 32) {
    for (int l = 0; l < 8; ++l) {
      int idx = l * 256 + tid; int r = idx >> 5, c = idx & 31;
      xs[r][c] = xb[(size_t)r * HH + k0 + c];
    }
    for (int l = 0; l < 8; ++l) {
      int idx = l * 256 + tid; int r = idx >> 6, c = idx & 63;
      wsm[r][c] = tw1[(size_t)(k0 + r) * HHALF + j0 + c];
    }
    __syncthreads();
    for (int kk = 0; kk < 32; ++kk) {
      float xv[4], wv[4];
      for (int i = 0; i < 4; ++i) xv[i] = xs[tr + i * 16][kk];
      for (int j = 0; j < 4; ++j) wv[j] = wsm[kk][tc + j * 16];
      for (int i = 0; i < 4; ++i)
        for (int j = 0; j < 4; ++j) acc[i][j] += xv[i] * wv[j];
    }
    __syncthreads();
  }
  for (int i = 0; i < 4; ++i)
    for (int j = 0; j < 4; ++j) {
      float aa = acc[i][j];
      ths[tr + i * 16][tc + j * 16] = 0.5f * aa * (1.0f + erff(aa * 0.70710678f));
    }
  __syncthreads();
  float* lp = lpart + (size_t)nc * (BSZ * EE);
  for (int l = 0; l < 4; ++l) {
    int idx = l * 256 + tid; int t = idx >> 4, e = idx & 15;
    float s = 0;
    for (int jj = 0; jj < 64; ++jj) s += ths[t][jj] * tw2[(size_t)(j0 + jj) * EE + e];
    lp[(t0 + t) * EE + e] = s;
  }
}

// ---------------- K8: token softmax + routing write + usage partials ----------------
__global__ __launch_bounds__(64) void k_toksoft(const float* __restrict__ lpart,
    const float* __restrict__ tb2, const int* __restrict__ flags,
    float* __restrict__ routing, double* __restrict__ upart) {
  int fb = flags[NB];
  if (fb < 0) return;
  int b = fb >> 3, n = fb & 7;
  int w = blockIdx.x;
  int t = w * 64 + threadIdx.x;
  float l[EE];
  for (int e = 0; e < EE; ++e) {
    float s = tb2[e];
    for (int nc = 0; nc < 16; ++nc) s += lpart[(size_t)nc * (BSZ * EE) + t * EE + e];
    l[e] = s;
  }
  float mx = l[0];
  for (int e = 1; e < EE; ++e) mx = fmaxf(mx, l[e]);
  float se = 0;
  for (int e = 0; e < EE; ++e) { l[e] = expf(l[e] - mx); se += l[e]; }
  float inv = 1.0f / se;
  for (int e = 0; e < EE; ++e) l[e] *= inv;
  float4* orow = (float4*)(routing + ((size_t)(b * SS + n * BSZ + t) * EE));
  orow[0] = make_float4(l[0], l[1], l[2], l[3]);
  orow[1] = make_float4(l[4], l[5], l[6], l[7]);
  orow[2] = make_float4(l[8], l[9], l[10], l[11]);
  orow[3] = make_float4(l[12], l[13], l[14], l[15]);
  for (int e = 0; e < EE; ++e) {
    double v = (double)l[e];
    for (int o = 32; o; o >>= 1) v += __shfl_down(v, o);
    if (threadIdx.x == 0) upart[w * EE + e] = v;
  }
}

// ---------------- K9: aux KL scalar (parallel staging, LDS) ----------------
__global__ __launch_bounds__(256) void k_aux(const double* __restrict__ upart,
    const int* __restrict__ flags, const float* __restrict__ bwv, const int* __restrict__ bwi,
    float* __restrict__ outaux) {
  __shared__ double up[16][EE];
  __shared__ double blkc[NB];
  __shared__ int    blke[NB];
  __shared__ double us[EE];
  int tid = threadIdx.x;
  int fb = flags[NB];
  if (fb >= 0) up[tid >> 4][tid & 15] = upart[tid];
  if (tid < NB) {
    int f = flags[tid];
    blkc[tid] = (f == 2) ? (double)BSZ * (double)bwv[tid] : 0.0;
    blke[tid] = (f == 2) ? bwi[tid] : -1;
  }
  __syncthreads();
  if (tid < EE) {
    double s = 0;
    if (fb >= 0) for (int w = 0; w < 16; ++w) s += up[w][tid];
    for (int i = 0; i < NB; ++i) if (blke[i] == tid) s += blkc[i];
    us[tid] = s;
  }
  __syncthreads();
  if (tid == 0) {
    double aux = 0;
    const double target = 1.0 / EE;
    for (int e = 0; e < EE; ++e) {
      double u = us[e] / (double)(BB * SS);
      aux += target * log(target / (u + 1e-10));
    }
    *outaux = (float)aux;
  }
}

extern "C" void kernel_launch(void* const* d_in, const int* in_sizes, int n_in,
                              void* d_out, int out_size, void* d_ws, size_t ws_size,
                              hipStream_t stream) {
  const float* x   = (const float*)d_in[0];
  const float* bw1 = (const float*)d_in[1];
  const float* bb1 = (const float*)d_in[2];
  const float* lng = (const float*)d_in[3];
  const float* lnb = (const float*)d_in[4];
  const float* bw2 = (const float*)d_in[5];
  const float* bb2 = (const float*)d_in[6];
  const float* tw1 = (const float*)d_in[7];
  const float* tb1 = (const float*)d_in[8];
  const float* tw2 = (const float*)d_in[9];
  const float* tb2 = (const float*)d_in[10];
  float* routing = (float*)d_out;
  float* outaux = routing + (size_t)BB * SS * EE;

  char* w = (char*)d_ws;
  const size_t br_sz    = (size_t)NB * HH * 8;          // 512 KB
  const size_t g1_sz    = (size_t)KQ * NB * BRD_ * 8;   // 1 MB
  const size_t lpart_sz = 16 * (size_t)BSZ * EE * 4;    // 1 MB
  const size_t upart_sz = 16 * EE * 8;
  const size_t tail_sz  = br_sz + g1_sz + lpart_sz + upart_sz + NB * 8 + 3 * 256 + 1024;
  int TC = 32;  // t-chunks per block for the mean kernel (parallelism)
  while (TC > 2 && ((size_t)NB * TC * HH * 8 + tail_sz > ws_size)) TC >>= 1;
  int rows = BSZ / TC;

  size_t off = 0;
  double* part  = (double*)(w + off); off += (size_t)NB * TC * HH * 8;
  double* br    = (double*)(w + off); off += br_sz;
  double* g1p   = (double*)(w + off); off += g1_sz;
  float*  lpart = (float*) (w + off); off += lpart_sz;
  double* upart = (double*)(w + off); off += upart_sz;
  double* ent   = (double*)(w + off); off += NB * 8;
  float*  bwv   = (float*) (w + off); off += 256;
  int*    bwi   = (int*)   (w + off); off += 256;
  int*    flags = (int*)   (w + off); off += 256;

  hipLaunchKernelGGL(k_bmean,   dim3(NB * TC), dim3(256), 0, stream, x, part, TC, rows);
  hipLaunchKernelGGL(k_brred,   dim3(NB),      dim3(256), 0, stream, part, TC, br);
  hipLaunchKernelGGL(k_g1,      dim3(64),      dim3(256), 0, stream, br, bw1, g1p);
  hipLaunchKernelGGL(k_router2, dim3(NB),      dim3(256), 0, stream, g1p,
                     bb1, lng, lnb, bw2, bb2, ent, bwv, bwi);
  hipLaunchKernelGGL(k_flags,   dim3(1),       dim3(64),  0, stream, ent, flags);
  hipLaunchKernelGGL(k_fill,    dim3(NB * 8),  dim3(256), 0, stream, flags, bwv, bwi, routing);
  hipLaunchKernelGGL(k_tokgemm, dim3(256),     dim3(256), 0, stream, x, tw1, tb1, tw2, flags, lpart);
  hipLaunchKernelGGL(k_toksoft, dim3(16),      dim3(64),  0, stream, lpart, tb2, flags, routing, upart);
  hipLaunchKernelGGL(k_aux,     dim3(1),       dim3(256), 0, stream, upart, flags, bwv, bwi, outaux);
}

// Round 4
// 109.535 us; speedup vs baseline: 1.4110x; 1.4110x over previous
//
#include <hip/hip_runtime.h>
#include <math.h>

#define BB 4
#define SS 8192
#define HH 2048
#define EE 16
#define BRD_ 256
#define BSZ 1024   /* block size from _adjust(8192) */
#define NN 8       /* SS/BSZ */
#define NB 32      /* BB*NN */
#define MAXTOK 1720 /* int(8192*0.21000000000000002) */
#define KBUD 1
#define HHALF 1024
#define KQ 16      /* K-split for GEMM1 */
#define TC 16      /* t-chunks per block for the mean kernel */
#define ROWS 64    /* BSZ / TC */

// ---------------- K1: block mean partial sums (memory-bound floor) ----------------
__global__ __launch_bounds__(256) void k_bmean(const float* __restrict__ x,
                                               double* __restrict__ part) {
  int wg = blockIdx.x;          // NB*TC = 512 wgs
  int bn = wg >> 4, tc = wg & 15;
  int b = bn >> 3, n = bn & 7;
  int tid = threadIdx.x;
  const float* base = x + ((size_t)(b * SS + n * BSZ + tc * ROWS) * HH);
  double a0=0,a1=0,a2=0,a3=0,a4=0,a5=0,a6=0,a7=0;
  #pragma unroll 4
  for (int t = 0; t < ROWS; ++t) {
    const float4* r = (const float4*)(base + (size_t)t * HH);
    float4 u = r[tid];        // h = tid*4 .. +3
    float4 v = r[tid + 256];  // h = 1024 + tid*4 .. +3
    a0 += u.x; a1 += u.y; a2 += u.z; a3 += u.w;
    a4 += v.x; a5 += v.y; a6 += v.z; a7 += v.w;
  }
  double* p = part + ((size_t)bn * TC + tc) * HH;
  int hA = tid * 4, hB = 1024 + tid * 4;
  p[hA] = a0; p[hA+1] = a1; p[hA+2] = a2; p[hA+3] = a3;
  p[hB] = a4; p[hB+1] = a5; p[hB+2] = a6; p[hB+3] = a7;
}

// ---------------- K2: fused partial-reduce + GEMM1 [32,2048]x[2048,256] ----------------
// 32 wgs: kq = bid>>1 (K-slice of 128), jt = bid&1 (column half of 128).
__global__ __launch_bounds__(256) void k_g1(const double* __restrict__ part,
    const float* __restrict__ bw1, double* __restrict__ g1part) {
  __shared__ double brs[NB][128];  // 32 KB: block means for this K-slice
  int bid = blockIdx.x;
  int kq = bid >> 1, jt = bid & 1;
  int tid = threadIdx.x;
  int k0 = kq * 128;
  // Staging+reduce: 4096 elements (32 bn x 128 k), 16 per thread, all loads independent.
  #pragma unroll
  for (int i = 0; i < 16; ++i) {
    int e = i * 256 + tid;
    int bn = e >> 7, k = e & 127;
    const double* pp = part + ((size_t)bn * TC) * HH + k0 + k;
    double s = 0;
    #pragma unroll
    for (int tc = 0; tc < TC; ++tc) s += pp[(size_t)tc * HH];  // serial adds, parallel loads
    brs[bn][k] = s * (1.0 / BSZ);
  }
  __syncthreads();
  // Compute: thread = (column j, bn half). 16 fp64 accumulators.
  int j = jt * 128 + (tid & 127);
  int bh = (tid >> 7) * 16;
  double acc[16];
  #pragma unroll
  for (int r = 0; r < 16; ++r) acc[r] = 0;
  const float* wp = bw1 + (size_t)k0 * BRD_ + j;
  #pragma unroll 2
  for (int k = 0; k < 128; ++k) {
    double wv = (double)wp[(size_t)k * BRD_];   // wave: 64 consecutive floats
    #pragma unroll
    for (int r = 0; r < 16; ++r) acc[r] += brs[bh + r][k] * wv;  // LDS broadcast
  }
  #pragma unroll
  for (int r = 0; r < 16; ++r)
    g1part[((size_t)kq * NB + bh + r) * BRD_ + j] = acc[r];
}

// ---------------- K3: per-block LN -> GELU -> GEMM2 -> softmax/entropy/argmax ----------------
__global__ __launch_bounds__(256) void k_router2(const double* __restrict__ g1part,
    const float* __restrict__ bb1, const float* __restrict__ lng, const float* __restrict__ lnb,
    const float* __restrict__ bw2, const float* __restrict__ bb2,
    double* __restrict__ ent, float* __restrict__ bwv, int* __restrict__ bwi) {
  __shared__ double tg[BRD_];
  __shared__ double p3[16][EE];
  __shared__ double red[4];
  __shared__ double l2[EE];
  __shared__ double bcast;
  int bn = blockIdx.x, tid = threadIdx.x;

  double a = (double)bb1[tid];
  #pragma unroll
  for (int kq = 0; kq < KQ; ++kq) a += g1part[((size_t)kq * NB + bn) * BRD_ + tid];

  // LayerNorm over 256 outputs (eps=1e-5, population var)
  double v = a;
  for (int o = 32; o; o >>= 1) v += __shfl_down(v, o);
  if ((tid & 63) == 0) red[tid >> 6] = v;
  __syncthreads();
  if (tid == 0) bcast = (red[0] + red[1] + red[2] + red[3]) * (1.0 / BRD_);
  __syncthreads();
  double m = bcast;
  double d = a - m;
  v = d * d;
  for (int o = 32; o; o >>= 1) v += __shfl_down(v, o);
  if ((tid & 63) == 0) red[tid >> 6] = v;
  __syncthreads();
  if (tid == 0) bcast = (red[0] + red[1] + red[2] + red[3]) * (1.0 / BRD_);
  __syncthreads();
  double var = bcast;
  double xn = d / sqrt(var + 1e-5) * (double)lng[tid] + (double)lnb[tid];
  tg[tid] = 0.5 * xn * (1.0 + erf(xn * 0.7071067811865476));  // exact GELU
  __syncthreads();

  // GEMM2 [1,256]x[256,16], thread = (j-chunk, expert)
  {
    int e = tid & 15, jc = tid >> 4;
    double s = 0;
    const float* w2 = bw2 + (size_t)(jc * 16) * EE + e;
    #pragma unroll
    for (int jj = 0; jj < 16; ++jj) s += tg[jc * 16 + jj] * (double)w2[jj * EE];
    p3[jc][e] = s;
  }
  __syncthreads();
  if (tid < EE) {
    double acc = (double)bb2[tid];
    #pragma unroll
    for (int jc = 0; jc < 16; ++jc) acc += p3[jc][tid];
    l2[tid] = acc;
  }
  __syncthreads();

  // softmax / entropy / argmax: lanes 0..15 of wave 0, shuffle reductions
  if (tid < 64) {
    int e = tid & 15;
    double le = l2[e];
    double mx = le;
    #pragma unroll
    for (int o = 1; o < 16; o <<= 1) mx = fmax(mx, __shfl_xor(mx, o));
    double pe = exp(le - mx);
    double se = pe;
    #pragma unroll
    for (int o = 1; o < 16; o <<= 1) se += __shfl_xor(se, o);
    double pr = pe / se;
    double q = pr + 1e-10;
    double term = -q * log(q);
    double es = term;
    #pragma unroll
    for (int o = 1; o < 16; o <<= 1) es += __shfl_xor(es, o);
    double mp = pr;
    #pragma unroll
    for (int o = 1; o < 16; o <<= 1) mp = fmax(mp, __shfl_xor(mp, o));
    unsigned long long eqm = __ballot((tid < 16) && (pr == mp));
    if (tid == 0) {
      ent[bn] = es / log(16.0);
      bwv[bn] = (float)mp;
      bwi[bn] = __ffsll(eqm) - 1;   // first max index, matches argmax
    }
  }
}

// ---------------- K4: mask logic, wave-parallel (KBUD==1 -> kth = max of selected) --------
__global__ void k_flags(const double* __restrict__ ent, int* __restrict__ flags) {
  int l = threadIdx.x;  // 64 lanes, one wave
  const double THR = 0.6 * 1.1;  // 0.66000000000000003
  double e = (l < NB) ? ent[l] : -INFINITY;
  bool m1 = (l < NB) && (e > THR);
  unsigned long long m1mask = __ballot(m1);
  int th = __popcll(m1mask);
  double sel = m1 ? e : -INFINITY;
  for (int o = 32; o; o >>= 1) sel = fmax(sel, __shfl_xor(sel, o));
  double kth = sel;
  bool cond = (th >= 2);  // (th*1024>1720) && (th>0) && (1<th)  <=>  th>=2
  bool m2 = cond ? ((l < NB) && (e > kth)) : m1;
  unsigned long long m2mask = __ballot(m2);
  int cum = __popcll(m2mask & ((2ULL << l) - 1ULL)) * BSZ;  // inclusive prefix
  bool tf = m2 && (cum <= MAXTOK);
  bool bf = (l < NB) && ((!m1) || (m2 && !tf));
  if (l < NB) flags[l] = tf ? 1 : (bf ? 2 : 0);
  unsigned long long tfmask = __ballot(tf);
  if (l == 0) flags[NB] = tfmask ? (__ffsll((unsigned long long)tfmask) - 1) : -1;
}

// ---------------- K5: fill routing for block-routed / zero blocks ----------------
__global__ __launch_bounds__(256) void k_fill(const int* __restrict__ flags,
    const float* __restrict__ bwv, const int* __restrict__ bwi, float* __restrict__ routing) {
  int wg = blockIdx.x;
  int bn = wg >> 3, seg = wg & 7;
  int fl = flags[bn];
  if (fl == 1) return;  // token GEMM path writes these
  int b = bn >> 3, n = bn & 7;
  float4 z = make_float4(0.f, 0.f, 0.f, 0.f);
  float4 val = z;
  int c_hit = -1;
  if (fl == 2) {
    int ai = bwi[bn];
    c_hit = ai >> 2;
    ((float*)&val)[ai & 3] = bwv[bn];
  }
  float4* out = (float4*)(routing + ((size_t)(b * SS + n * BSZ + seg * 128) * EE));
  int tid = threadIdx.x;
  #pragma unroll
  for (int l = 0; l < 2; ++l) {
    int idx = l * 256 + tid;  // 512 float4 = 128 rows x 4
    int c = idx & 3;
    out[idx] = (c == c_hit) ? val : z;
  }
}

// ---------------- K6: token GEMM (only the flagged block; others exit) ----------------
__global__ __launch_bounds__(256) void k_tokgemm(const float* __restrict__ x,
    const float* __restrict__ tw1, const float* __restrict__ tb1, const float* __restrict__ tw2,
    const int* __restrict__ flags, float* __restrict__ lpart) {
  int fb = flags[NB];
  if (fb < 0) return;
  int b = fb >> 3, n = fb & 7;
  int tg = blockIdx.x >> 4, nc = blockIdx.x & 15;
  int t0 = tg * 64, j0 = nc * 64;
  const float* xb = x + ((size_t)(b * SS + n * BSZ + t0) * HH);
  __shared__ float xs[64][33];
  __shared__ float wsm[32][65];
  __shared__ float ths[64][65];
  int tid = threadIdx.x;
  int tr = tid >> 4, tc = tid & 15;
  float acc[4][4];
  for (int i = 0; i < 4; ++i)
    for (int j = 0; j < 4; ++j) acc[i][j] = tb1[j0 + tc + j * 16];
  for (int k0 = 0; k0 < HH; k0 += 32) {
    #pragma unroll
    for (int l = 0; l < 8; ++l) {
      int idx = l * 256 + tid; int r = idx >> 5, c = idx & 31;
      xs[r][c] = xb[(size_t)r * HH + k0 + c];
    }
    #pragma unroll
    for (int l = 0; l < 8; ++l) {
      int idx = l * 256 + tid; int r = idx >> 6, c = idx & 63;
      wsm[r][c] = tw1[(size_t)(k0 + r) * HHALF + j0 + c];
    }
    __syncthreads();
    #pragma unroll
    for (int kk = 0; kk < 32; ++kk) {
      float xv[4], wv[4];
      for (int i = 0; i < 4; ++i) xv[i] = xs[tr + i * 16][kk];
      for (int j = 0; j < 4; ++j) wv[j] = wsm[kk][tc + j * 16];
      for (int i = 0; i < 4; ++i)
        for (int j = 0; j < 4; ++j) acc[i][j] += xv[i] * wv[j];
    }
    __syncthreads();
  }
  for (int i = 0; i < 4; ++i)
    for (int j = 0; j < 4; ++j) {
      float aa = acc[i][j];
      ths[tr + i * 16][tc + j * 16] = 0.5f * aa * (1.0f + erff(aa * 0.70710678f));
    }
  __syncthreads();
  float* lp = lpart + (size_t)nc * (BSZ * EE);
  #pragma unroll
  for (int l = 0; l < 4; ++l) {
    int idx = l * 256 + tid; int t = idx >> 4, e = idx & 15;
    float s = 0;
    #pragma unroll
    for (int jj = 0; jj < 64; ++jj) s += ths[t][jj] * tw2[(size_t)(j0 + jj) * EE + e];
    lp[(t0 + t) * EE + e] = s;
  }
}

// ---------------- K7: token softmax + routing write + usage partials ----------------
__global__ __launch_bounds__(64) void k_toksoft(const float* __restrict__ lpart,
    const float* __restrict__ tb2, const int* __restrict__ flags,
    float* __restrict__ routing, double* __restrict__ upart) {
  int fb = flags[NB];
  if (fb < 0) return;
  int b = fb >> 3, n = fb & 7;
  int w = blockIdx.x;
  int t = w * 64 + threadIdx.x;
  float l[EE];
  #pragma unroll
  for (int e = 0; e < EE; ++e) {
    float s = tb2[e];
    #pragma unroll
    for (int nc = 0; nc < 16; ++nc) s += lpart[(size_t)nc * (BSZ * EE) + t * EE + e];
    l[e] = s;
  }
  float mx = l[0];
  for (int e = 1; e < EE; ++e) mx = fmaxf(mx, l[e]);
  float se = 0;
  for (int e = 0; e < EE; ++e) { l[e] = expf(l[e] - mx); se += l[e]; }
  float inv = 1.0f / se;
  for (int e = 0; e < EE; ++e) l[e] *= inv;
  float4* orow = (float4*)(routing + ((size_t)(b * SS + n * BSZ + t) * EE));
  orow[0] = make_float4(l[0], l[1], l[2], l[3]);
  orow[1] = make_float4(l[4], l[5], l[6], l[7]);
  orow[2] = make_float4(l[8], l[9], l[10], l[11]);
  orow[3] = make_float4(l[12], l[13], l[14], l[15]);
  for (int e = 0; e < EE; ++e) {
    double v = (double)l[e];
    for (int o = 32; o; o >>= 1) v += __shfl_down(v, o);
    if (threadIdx.x == 0) upart[w * EE + e] = v;
  }
}

// ---------------- K8: aux KL scalar (parallel staging, LDS) ----------------
__global__ __launch_bounds__(256) void k_aux(const double* __restrict__ upart,
    const int* __restrict__ flags, const float* __restrict__ bwv, const int* __restrict__ bwi,
    float* __restrict__ outaux) {
  __shared__ double up[16][EE];
  __shared__ double blkc[NB];
  __shared__ int    blke[NB];
  __shared__ double us[EE];
  int tid = threadIdx.x;
  int fb = flags[NB];
  if (fb >= 0) up[tid >> 4][tid & 15] = upart[tid];
  if (tid < NB) {
    int f = flags[tid];
    blkc[tid] = (f == 2) ? (double)BSZ * (double)bwv[tid] : 0.0;
    blke[tid] = (f == 2) ? bwi[tid] : -1;
  }
  __syncthreads();
  if (tid < EE) {
    double s = 0;
    if (fb >= 0) for (int w = 0; w < 16; ++w) s += up[w][tid];
    for (int i = 0; i < NB; ++i) if (blke[i] == tid) s += blkc[i];
    us[tid] = s;
  }
  __syncthreads();
  if (tid == 0) {
    double aux = 0;
    const double target = 1.0 / EE;
    for (int e = 0; e < EE; ++e) {
      double u = us[e] / (double)(BB * SS);
      aux += target * log(target / (u + 1e-10));
    }
    *outaux = (float)aux;
  }
}

extern "C" void kernel_launch(void* const* d_in, const int* in_sizes, int n_in,
                              void* d_out, int out_size, void* d_ws, size_t ws_size,
                              hipStream_t stream) {
  const float* x   = (const float*)d_in[0];
  const float* bw1 = (const float*)d_in[1];
  const float* bb1 = (const float*)d_in[2];
  const float* lng = (const float*)d_in[3];
  const float* lnb = (const float*)d_in[4];
  const float* bw2 = (const float*)d_in[5];
  const float* bb2 = (const float*)d_in[6];
  const float* tw1 = (const float*)d_in[7];
  const float* tb1 = (const float*)d_in[8];
  const float* tw2 = (const float*)d_in[9];
  const float* tb2 = (const float*)d_in[10];
  float* routing = (float*)d_out;
  float* outaux = routing + (size_t)BB * SS * EE;

  char* w = (char*)d_ws;
  size_t off = 0;
  double* part  = (double*)(w + off); off += (size_t)NB * TC * HH * 8;   // 8 MB
  double* g1p   = (double*)(w + off); off += (size_t)KQ * NB * BRD_ * 8; // 1 MB
  float*  lpart = (float*) (w + off); off += 16 * (size_t)BSZ * EE * 4;  // 1 MB
  double* upart = (double*)(w + off); off += 16 * EE * 8;
  double* ent   = (double*)(w + off); off += NB * 8;
  float*  bwv   = (float*) (w + off); off += 256;
  int*    bwi   = (int*)   (w + off); off += 256;
  int*    flags = (int*)   (w + off); off += 256;

  hipLaunchKernelGGL(k_bmean,   dim3(NB * TC), dim3(256), 0, stream, x, part);
  hipLaunchKernelGGL(k_g1,      dim3(32),      dim3(256), 0, stream, part, bw1, g1p);
  hipLaunchKernelGGL(k_router2, dim3(NB),      dim3(256), 0, stream, g1p,
                     bb1, lng, lnb, bw2, bb2, ent, bwv, bwi);
  hipLaunchKernelGGL(k_flags,   dim3(1),       dim3(64),  0, stream, ent, flags);
  hipLaunchKernelGGL(k_fill,    dim3(NB * 8),  dim3(256), 0, stream, flags, bwv, bwi, routing);
  hipLaunchKernelGGL(k_tokgemm, dim3(256),     dim3(256), 0, stream, x, tw1, tb1, tw2, flags, lpart);
  hipLaunchKernelGGL(k_toksoft, dim3(16),      dim3(64),  0, stream, lpart, tb2, flags, routing, upart);
  hipLaunchKernelGGL(k_aux,     dim3(1),       dim3(256), 0, stream, upart, flags, bwv, bwi, outaux);
}

// Round 5
// 74.508 us; speedup vs baseline: 2.0743x; 1.4701x over previous
//
#include <hip/hip_runtime.h>
#include <math.h>

#define BB 4
#define SS 8192
#define HH 2048
#define EE 16
#define BRD_ 256
#define BSZ 1024   /* block size from _adjust(8192) */
#define NN 8       /* SS/BSZ */
#define NB 32      /* BB*NN */
#define MAXTOK 1720 /* int(8192*0.21000000000000002) */
#define HHALF 1024
#define TC 16      /* t-chunks per block for the mean kernel */
#define ROWS 64    /* BSZ / TC */
#define KSP 32     /* k-slices for GEMM1 */
#define KL 64      /* HH / KSP */
#define JL 64      /* j-slice width */

// ---- inline wave-parallel flag logic (lanes 0..63 of one wave; NB=32, KBUD=1) ----
// returns: per-lane flag (valid for l<NB) and fb (uniform across wave)
__device__ inline void wave_flags(const double* __restrict__ ent, int l,
                                  int& flag_out, int& fb_out) {
  const double THR = 0.6 * 1.1;  // 0.66000000000000003
  double e = (l < NB) ? ent[l] : -INFINITY;
  bool m1 = (l < NB) && (e > THR);
  unsigned long long m1mask = __ballot(m1);
  int th = __popcll(m1mask);
  double sel = m1 ? e : -INFINITY;
  #pragma unroll
  for (int o = 32; o; o >>= 1) sel = fmax(sel, __shfl_xor(sel, o));
  // cond = (th*1024>1720)&&(th>0)&&(1<th) <=> th>=2 ; kth = max of selected (KBUD=1)
  bool m2 = (th >= 2) ? ((l < NB) && (e > sel)) : m1;
  unsigned long long m2mask = __ballot(m2);
  int cum = __popcll(m2mask & ((2ULL << l) - 1ULL)) * BSZ;  // inclusive prefix
  bool tf = m2 && (cum <= MAXTOK);
  bool bf = (l < NB) && ((!m1) || (m2 && !tf));
  flag_out = tf ? 1 : (bf ? 2 : 0);
  unsigned long long tfmask = __ballot(tf);
  fb_out = tfmask ? (__ffsll(tfmask) - 1) : -1;
}

// ---------------- K1: block mean partial sums (memory-bound floor) ----------------
__global__ __launch_bounds__(256) void k_bmean(const float* __restrict__ x,
                                               double* __restrict__ part) {
  int wg = blockIdx.x;          // NB*TC = 512 wgs
  int bn = wg >> 4, tc = wg & 15;
  int b = bn >> 3, n = bn & 7;
  int tid = threadIdx.x;
  const float* base = x + ((size_t)(b * SS + n * BSZ + tc * ROWS) * HH);
  double a0=0,a1=0,a2=0,a3=0,a4=0,a5=0,a6=0,a7=0;
  #pragma unroll 4
  for (int t = 0; t < ROWS; ++t) {
    const float4* r = (const float4*)(base + (size_t)t * HH);
    float4 u = r[tid];        // h = tid*4 .. +3
    float4 v = r[tid + 256];  // h = 1024 + tid*4 .. +3
    a0 += u.x; a1 += u.y; a2 += u.z; a3 += u.w;
    a4 += v.x; a5 += v.y; a6 += v.z; a7 += v.w;
  }
  double* p = part + ((size_t)bn * TC + tc) * HH;
  int hA = tid * 4, hB = 1024 + tid * 4;
  p[hA] = a0; p[hA+1] = a1; p[hA+2] = a2; p[hA+3] = a3;
  p[hB] = a4; p[hB+1] = a5; p[hB+2] = a6; p[hB+3] = a7;
}

// ---------------- K2: reduce+GEMM1, 128 wgs = 32 k-slices x 4 j-slices ----------------
__global__ __launch_bounds__(256) void k_g1(const double* __restrict__ part,
    const float* __restrict__ bw1, double* __restrict__ g1part) {
  __shared__ double brs[NB][KL];  // 16 KB block means, this k-slice
  __shared__ float  wsm[KL][JL];  // 16 KB bw1 slice
  int bid = blockIdx.x;
  int kq = bid >> 2, jt = bid & 3;
  int k0 = kq * KL, j0 = jt * JL;
  int tid = threadIdx.x;
  // stage block means: 2048 elems, 8/thread, 128 independent loads each
  #pragma unroll
  for (int i = 0; i < 8; ++i) {
    int e = i * 256 + tid;
    int bn = e >> 6, k = e & 63;
    const double* pp = part + ((size_t)bn * TC) * HH + k0 + k;
    double s = 0;
    #pragma unroll
    for (int tc = 0; tc < TC; ++tc) s += pp[(size_t)tc * HH];
    brs[bn][k] = s * (1.0 / BSZ);
  }
  // stage bw1 slice: 4096 floats, 4 float4/thread
  #pragma unroll
  for (int i = 0; i < 4; ++i) {
    int f = i * 256 + tid;
    int r = f >> 4, c4 = f & 15;
    float4 v = *(const float4*)(bw1 + (size_t)(k0 + r) * BRD_ + j0 + c4 * 4);
    *(float4*)&wsm[r][c4 * 4] = v;
  }
  __syncthreads();
  // compute: thread = (j, bn-octet): 8 fp64 accumulators
  int j = tid & 63;
  int bh = (tid >> 6) * 8;
  double acc[8];
  #pragma unroll
  for (int r = 0; r < 8; ++r) acc[r] = 0;
  #pragma unroll 8
  for (int k = 0; k < KL; ++k) {
    double wv = (double)wsm[k][j];           // conflict-free
    #pragma unroll
    for (int r = 0; r < 8; ++r) acc[r] += brs[bh + r][k] * wv;  // broadcast
  }
  #pragma unroll
  for (int r = 0; r < 8; ++r)
    g1part[((size_t)kq * NB + bh + r) * BRD_ + j0 + j] = acc[r];
}

// ---------------- K3: per-block LN -> GELU -> GEMM2 -> softmax/entropy/argmax ----------------
__global__ __launch_bounds__(256) void k_router2(const double* __restrict__ g1part,
    const float* __restrict__ bb1, const float* __restrict__ lng, const float* __restrict__ lnb,
    const float* __restrict__ bw2, const float* __restrict__ bb2,
    double* __restrict__ ent, float* __restrict__ bwv, int* __restrict__ bwi) {
  __shared__ double tg[BRD_];
  __shared__ double p3[16][EE];
  __shared__ double red[4];
  __shared__ double l2[EE];
  __shared__ double bcast;
  int bn = blockIdx.x, tid = threadIdx.x;

  double a = (double)bb1[tid];
  #pragma unroll
  for (int kq = 0; kq < KSP; ++kq) a += g1part[((size_t)kq * NB + bn) * BRD_ + tid];

  // LayerNorm over 256 outputs (eps=1e-5, population var)
  double v = a;
  for (int o = 32; o; o >>= 1) v += __shfl_down(v, o);
  if ((tid & 63) == 0) red[tid >> 6] = v;
  __syncthreads();
  if (tid == 0) bcast = (red[0] + red[1] + red[2] + red[3]) * (1.0 / BRD_);
  __syncthreads();
  double m = bcast;
  double d = a - m;
  v = d * d;
  for (int o = 32; o; o >>= 1) v += __shfl_down(v, o);
  if ((tid & 63) == 0) red[tid >> 6] = v;
  __syncthreads();
  if (tid == 0) bcast = (red[0] + red[1] + red[2] + red[3]) * (1.0 / BRD_);
  __syncthreads();
  double var = bcast;
  double xn = d / sqrt(var + 1e-5) * (double)lng[tid] + (double)lnb[tid];
  tg[tid] = 0.5 * xn * (1.0 + erf(xn * 0.7071067811865476));  // exact GELU
  __syncthreads();

  // GEMM2 [1,256]x[256,16], thread = (j-chunk, expert)
  {
    int e = tid & 15, jc = tid >> 4;
    double s = 0;
    const float* w2 = bw2 + (size_t)(jc * 16) * EE + e;
    #pragma unroll
    for (int jj = 0; jj < 16; ++jj) s += tg[jc * 16 + jj] * (double)w2[jj * EE];
    p3[jc][e] = s;
  }
  __syncthreads();
  if (tid < EE) {
    double acc = (double)bb2[tid];
    #pragma unroll
    for (int jc = 0; jc < 16; ++jc) acc += p3[jc][tid];
    l2[tid] = acc;
  }
  __syncthreads();

  // softmax / entropy / argmax: lanes 0..15 of wave 0, shuffle reductions
  if (tid < 64) {
    int e = tid & 15;
    double le = l2[e];
    double mx = le;
    #pragma unroll
    for (int o = 1; o < 16; o <<= 1) mx = fmax(mx, __shfl_xor(mx, o));
    double pe = exp(le - mx);
    double se = pe;
    #pragma unroll
    for (int o = 1; o < 16; o <<= 1) se += __shfl_xor(se, o);
    double pr = pe / se;
    double q = pr + 1e-10;
    double term = -q * log(q);
    double es = term;
    #pragma unroll
    for (int o = 1; o < 16; o <<= 1) es += __shfl_xor(es, o);
    double mp = pr;
    #pragma unroll
    for (int o = 1; o < 16; o <<= 1) mp = fmax(mp, __shfl_xor(mp, o));
    unsigned long long eqm = __ballot((tid < 16) && (pr == mp));
    if (tid == 0) {
      ent[bn] = es / log(16.0);
      bwv[bn] = (float)mp;
      bwi[bn] = __ffsll(eqm) - 1;   // first max index, matches argmax
    }
  }
}

// ---------------- K4: merged fill + token-GEMM (512 wgs; flags inline) ----------------
__global__ __launch_bounds__(256) void k_out(const double* __restrict__ ent,
    const float* __restrict__ bwv, const int* __restrict__ bwi,
    const float* __restrict__ x, const float* __restrict__ tw1, const float* __restrict__ tb1,
    const float* __restrict__ tw2, float* __restrict__ routing, float* __restrict__ lpart) {
  __shared__ int flg_s[NB + 1];
  __shared__ float xs[64][33];
  __shared__ float wsm[32][65];
  __shared__ float ths[64][65];
  int tid = threadIdx.x;
  int bid = blockIdx.x;
  if (tid < 64) {
    int f, fb;
    wave_flags(ent, tid, f, fb);
    if (tid < NB) flg_s[tid] = f;
    if (tid == 0) flg_s[NB] = fb;
  }
  __syncthreads();

  if (bid < 256) {   // ---- fill path: wg = (bn, seg) ----
    int bn = bid >> 3, seg = bid & 7;
    int fl = flg_s[bn];
    if (fl == 1) return;  // token path writes these rows
    int b = bn >> 3, n = bn & 7;
    float4 z = make_float4(0.f, 0.f, 0.f, 0.f);
    float4 val = z;
    int c_hit = -1;
    if (fl == 2) {
      int ai = bwi[bn];
      c_hit = ai >> 2;
      ((float*)&val)[ai & 3] = bwv[bn];
    }
    float4* out = (float4*)(routing + ((size_t)(b * SS + n * BSZ + seg * 128) * EE));
    #pragma unroll
    for (int l = 0; l < 2; ++l) {
      int idx = l * 256 + tid;  // 512 float4 = 128 rows x 4
      int c = idx & 3;
      out[idx] = (c == c_hit) ? val : z;
    }
    return;
  }

  // ---- token GEMM path: wg = (tg, nc) ----
  int fb = flg_s[NB];
  if (fb < 0) return;
  int b = fb >> 3, n = fb & 7;
  int tb = bid - 256;
  int tg = tb >> 4, nc = tb & 15;
  int t0 = tg * 64, j0 = nc * 64;
  const float* xb = x + ((size_t)(b * SS + n * BSZ + t0) * HH);
  int tr = tid >> 4, tc = tid & 15;
  float acc[4][4];
  for (int i = 0; i < 4; ++i)
    for (int j = 0; j < 4; ++j) acc[i][j] = tb1[j0 + tc + j * 16];
  for (int k0 = 0; k0 < HH; k0 += 32) {
    #pragma unroll
    for (int l = 0; l < 8; ++l) {
      int idx = l * 256 + tid; int r = idx >> 5, c = idx & 31;
      xs[r][c] = xb[(size_t)r * HH + k0 + c];
    }
    #pragma unroll
    for (int l = 0; l < 8; ++l) {
      int idx = l * 256 + tid; int r = idx >> 6, c = idx & 63;
      wsm[r][c] = tw1[(size_t)(k0 + r) * HHALF + j0 + c];
    }
    __syncthreads();
    #pragma unroll
    for (int kk = 0; kk < 32; ++kk) {
      float xv[4], wv[4];
      for (int i = 0; i < 4; ++i) xv[i] = xs[tr + i * 16][kk];
      for (int j = 0; j < 4; ++j) wv[j] = wsm[kk][tc + j * 16];
      for (int i = 0; i < 4; ++i)
        for (int j = 0; j < 4; ++j) acc[i][j] += xv[i] * wv[j];
    }
    __syncthreads();
  }
  for (int i = 0; i < 4; ++i)
    for (int j = 0; j < 4; ++j) {
      float aa = acc[i][j];
      ths[tr + i * 16][tc + j * 16] = 0.5f * aa * (1.0f + erff(aa * 0.70710678f));
    }
  __syncthreads();
  float* lp = lpart + (size_t)nc * (BSZ * EE);
  #pragma unroll
  for (int l = 0; l < 4; ++l) {
    int idx = l * 256 + tid; int t = idx >> 4, e = idx & 15;
    float s = 0;
    #pragma unroll
    for (int jj = 0; jj < 64; ++jj) s += ths[t][jj] * tw2[(size_t)(j0 + jj) * EE + e];
    lp[(t0 + t) * EE + e] = s;
  }
}

// ---------------- K5: token softmax + routing write + usage partials ----------------
__global__ __launch_bounds__(64) void k_toksoft(const double* __restrict__ ent,
    const float* __restrict__ lpart, const float* __restrict__ tb2,
    float* __restrict__ routing, double* __restrict__ upart) {
  int tid = threadIdx.x;
  int f_unused, fb;
  wave_flags(ent, tid, f_unused, fb);
  if (fb < 0) return;
  int b = fb >> 3, n = fb & 7;
  int w = blockIdx.x;
  int t = w * 64 + tid;
  float l[EE];
  #pragma unroll
  for (int e = 0; e < EE; ++e) {
    float s = tb2[e];
    #pragma unroll
    for (int nc = 0; nc < 16; ++nc) s += lpart[(size_t)nc * (BSZ * EE) + t * EE + e];
    l[e] = s;
  }
  float mx = l[0];
  for (int e = 1; e < EE; ++e) mx = fmaxf(mx, l[e]);
  float se = 0;
  for (int e = 0; e < EE; ++e) { l[e] = expf(l[e] - mx); se += l[e]; }
  float inv = 1.0f / se;
  for (int e = 0; e < EE; ++e) l[e] *= inv;
  float4* orow = (float4*)(routing + ((size_t)(b * SS + n * BSZ + t) * EE));
  orow[0] = make_float4(l[0], l[1], l[2], l[3]);
  orow[1] = make_float4(l[4], l[5], l[6], l[7]);
  orow[2] = make_float4(l[8], l[9], l[10], l[11]);
  orow[3] = make_float4(l[12], l[13], l[14], l[15]);
  for (int e = 0; e < EE; ++e) {
    double v = (double)l[e];
    for (int o = 32; o; o >>= 1) v += __shfl_down(v, o);
    if (tid == 0) upart[w * EE + e] = v;
  }
}

// ---------------- K6: aux KL scalar (flags inline, parallel staging) ----------------
__global__ __launch_bounds__(256) void k_aux(const double* __restrict__ ent,
    const double* __restrict__ upart, const float* __restrict__ bwv,
    const int* __restrict__ bwi, float* __restrict__ outaux) {
  __shared__ int flg_s[NB + 1];
  __shared__ double up[16][EE];
  __shared__ double blkc[NB];
  __shared__ int    blke[NB];
  __shared__ double us[EE];
  int tid = threadIdx.x;
  if (tid < 64) {
    int f, fb;
    wave_flags(ent, tid, f, fb);
    if (tid < NB) flg_s[tid] = f;
    if (tid == 0) flg_s[NB] = fb;
  }
  __syncthreads();
  int fb = flg_s[NB];
  if (fb >= 0) up[tid >> 4][tid & 15] = upart[tid];
  if (tid < NB) {
    int f = flg_s[tid];
    blkc[tid] = (f == 2) ? (double)BSZ * (double)bwv[tid] : 0.0;
    blke[tid] = (f == 2) ? bwi[tid] : -1;
  }
  __syncthreads();
  if (tid < EE) {
    double s = 0;
    if (fb >= 0) for (int w = 0; w < 16; ++w) s += up[w][tid];
    for (int i = 0; i < NB; ++i) if (blke[i] == tid) s += blkc[i];
    us[tid] = s;
  }
  __syncthreads();
  if (tid == 0) {
    double aux = 0;
    const double target = 1.0 / EE;
    for (int e = 0; e < EE; ++e) {
      double u = us[e] / (double)(BB * SS);
      aux += target * log(target / (u + 1e-10));
    }
    *outaux = (float)aux;
  }
}

extern "C" void kernel_launch(void* const* d_in, const int* in_sizes, int n_in,
                              void* d_out, int out_size, void* d_ws, size_t ws_size,
                              hipStream_t stream) {
  const float* x   = (const float*)d_in[0];
  const float* bw1 = (const float*)d_in[1];
  const float* bb1 = (const float*)d_in[2];
  const float* lng = (const float*)d_in[3];
  const float* lnb = (const float*)d_in[4];
  const float* bw2 = (const float*)d_in[5];
  const float* bb2 = (const float*)d_in[6];
  const float* tw1 = (const float*)d_in[7];
  const float* tb1 = (const float*)d_in[8];
  const float* tw2 = (const float*)d_in[9];
  const float* tb2 = (const float*)d_in[10];
  float* routing = (float*)d_out;
  float* outaux = routing + (size_t)BB * SS * EE;

  char* w = (char*)d_ws;
  size_t off = 0;
  double* part  = (double*)(w + off); off += (size_t)NB * TC * HH * 8;    // 8 MB
  double* g1p   = (double*)(w + off); off += (size_t)KSP * NB * BRD_ * 8; // 2 MB
  float*  lpart = (float*) (w + off); off += 16 * (size_t)BSZ * EE * 4;   // 1 MB
  double* upart = (double*)(w + off); off += 16 * EE * 8;
  double* ent   = (double*)(w + off); off += NB * 8;
  float*  bwv   = (float*) (w + off); off += 256;
  int*    bwi   = (int*)   (w + off); off += 256;

  hipLaunchKernelGGL(k_bmean,   dim3(NB * TC), dim3(256), 0, stream, x, part);
  hipLaunchKernelGGL(k_g1,      dim3(128),     dim3(256), 0, stream, part, bw1, g1p);
  hipLaunchKernelGGL(k_router2, dim3(NB),      dim3(256), 0, stream, g1p,
                     bb1, lng, lnb, bw2, bb2, ent, bwv, bwi);
  hipLaunchKernelGGL(k_out,     dim3(512),     dim3(256), 0, stream, ent, bwv, bwi,
                     x, tw1, tb1, tw2, routing, lpart);
  hipLaunchKernelGGL(k_toksoft, dim3(16),      dim3(64),  0, stream, ent, lpart, tb2,
                     routing, upart);
  hipLaunchKernelGGL(k_aux,     dim3(1),       dim3(256), 0, stream, ent, upart, bwv, bwi, outaux);
}